// Round 22
// baseline (1502.311 us; speedup 1.0000x reference)
//
#include <hip/hip_runtime.h>
#include <hip/hip_cooperative_groups.h>

namespace cg = cooperative_groups;

// LDPC BP decoder, (3,6)-regular — single cooperative kernel version.
// Edge e (vn order) = 3v+j; c = e mod 8192, t = e div 8192, e = c + 8192t.
//
// r21 -> r22: fix compile error only (hipDeviceAttributeMultiprocessorCount
// spelling). Design unchanged: all 8 CN iterations + final VN in ONE
// cooperative launch with grid.sync() between phases. Math chain
// BIT-IDENTICAL to r20 (absmax must stay exactly 0.25).

constexpr int NUM_VNS   = 16384;
constexpr int NUM_CNS   = 8192;
constexpr int NUM_EDGES = 49152;
constexpr int BATCH     = 128;
constexpr int NUM_ITER  = 8;
constexpr float LLR_MAX = 20.0f;
constexpr float PHI_MIN = 8.5e-8f;
constexpr float PHI_MAX = 16.635532f;

// ---- full-accuracy reference primitives (table init + fallback path) ----
__device__ __forceinline__ double lean_exp(double x) {
    double t = x * 1.4426950408889634;
    double k = __builtin_rint(t);
    double r = __builtin_fma(-k, 0.6931471805599453, x);
    r = __builtin_fma(-k, 2.3190468138462996e-17, r);
    double p = 1.0 / 3628800.0;                  // Taylor deg 10, |r|<=0.347
    p = __builtin_fma(p, r, 1.0 / 362880.0);
    p = __builtin_fma(p, r, 1.0 / 40320.0);
    p = __builtin_fma(p, r, 1.0 / 5040.0);
    p = __builtin_fma(p, r, 1.0 / 720.0);
    p = __builtin_fma(p, r, 1.0 / 120.0);
    p = __builtin_fma(p, r, 1.0 / 24.0);
    p = __builtin_fma(p, r, 1.0 / 6.0);
    p = __builtin_fma(p, r, 0.5);
    p = __builtin_fma(p, r, 1.0);
    p = __builtin_fma(p, r, 1.0);
    int ik = (int)k;                              // k in [0,24]
    double s = __hiloint2double((1023 + ik) << 20, 0);
    return p * s;
}

__device__ __forceinline__ double lean_log(double v) {
    int hv = __double2hiint(v);
    int lv = __double2loint(v);
    int e  = (hv >> 20) - 1023;
    double m = __hiloint2double((hv & 0x000FFFFF) | 0x3FF00000, lv);
    if (m >= 1.4142135623730951) { m *= 0.5; e += 1; }   // m in [0.7071,1.4142)
    double t = m - 1.0;
    double d = t + 2.0;
    double r = (double)__builtin_amdgcn_rcpf((float)d);
    r = __builtin_fma(__builtin_fma(-d, r, 1.0), r, r);
    double u = t * r;
    double w = u * u;
    double P = 2.0 / 13.0;                        // 2*artanh: deg 6 in w
    P = __builtin_fma(P, w, 2.0 / 11.0);
    P = __builtin_fma(P, w, 2.0 / 9.0);
    P = __builtin_fma(P, w, 2.0 / 7.0);
    P = __builtin_fma(P, w, 2.0 / 5.0);
    P = __builtin_fma(P, w, 2.0 / 3.0);
    P = __builtin_fma(P, w, 2.0);
    double lm = u * P;
    return __builtin_fma((double)e, 0.6931471805599453, lm);
}

__device__ __forceinline__ float phi_f(float xf) {
    xf = fminf(fmaxf(xf, PHI_MIN), PHI_MAX);
    float exf = (float)lean_exp((double)xf);
    float af = exf + 1.0f;
    float bf = exf - 1.0f;
    float la = (float)lean_log((double)af);
    float lb = (float)lean_log((double)bf);
    return la - lb;
}

// ---- fast table primitives (main path) ----
constexpr double EXP_STEP = 0.0027076061740622864;  // double(ln2/256)
constexpr double EXP_INV  = 369.32993046757465;     // 256/ln2

// e^x, x in [0, 16.64]; rel err <= r^3/6 ~ 2^-31.2, and -> 0 as x -> 0.
__device__ __forceinline__ double fast_exp(double x, const double* et) {
    double kd = __builtin_rint(x * EXP_INV);
    double r  = __builtin_fma(-kd, EXP_STEP, x);     // |r| <= 0.001354
    int n = (int)kd;                                 // [0, 6145]
    double p = __builtin_fma(r, __builtin_fma(r, 0.5, 1.0), 1.0);  // deg 2
    double s = et[n & 255];                          // 2^(j/256)
    int sh = __double2hiint(s) + ((n >> 8) << 20);   // * 2^k
    s = __hiloint2double(sh, __double2loint(s));
    return p * s;
}

// log(v), v an exact f32 in [2^-23, 2^25]; abs err ~2^-34.
__device__ __forceinline__ double fast_log(double v, const double2* lt) {
    int hv = __double2hiint(v);
    int lv = __double2loint(v);
    int E  = (hv >> 20) - 1023;
    double m = __hiloint2double((hv & 0x000FFFFF) | 0x3FF00000, lv); // [1,2)
    int idx = (hv >> 12) & 255;
    double2 te = lt[idx];                            // {1/t, log t}
    double t = __hiloint2double(0x3FF00000 | (idx << 12), 0);        // 1+idx/256
    double d = m - t;                                // exact (Sterbenz)
    double f = d * te.x;                             // d / t, f in [0, 2^-8)
    double P = __builtin_fma(f, 1.0 / 3.0, -0.5);
    double q = __builtin_fma(f * f, P, f);           // log1p(f), deg 3
    return __builtin_fma((double)E, 0.6931471805599453, te.y + q);
}

__device__ __forceinline__ float phi_fast(float xf, const double2* lt,
                                          const double* et) {
    xf = fminf(fmaxf(xf, PHI_MIN), PHI_MAX);
    float exf = (float)fast_exp((double)xf, et);
    float af = exf + 1.0f;
    float bf = exf - 1.0f;
    float la = (float)fast_log((double)af, lt);
    float lb = (float)fast_log((double)bf, lt);
    return la - lb;
}

// ---- shared CN body (identical math to r20's cn_fused) ----
template<int FIRST>
__device__ __forceinline__ void cn_body(const float* __restrict__ llr,
                                        const float* __restrict__ msgIn,
                                        float* __restrict__ msgOut,
                                        int b, int c,
                                        const double2* lt, const double* et)
{
    const float* mi = msgIn + (size_t)b * NUM_EDGES;
    float* mo = msgOut + (size_t)b * NUM_EDGES;
    const float* lbp = llr + (size_t)b * NUM_VNS;

    float g[6];                                     // signed mags (sign in bit)
#pragma unroll
    for (int t = 0; t < 6; ++t) {
        int e = c + (t << 13);
        int v = (int)(((unsigned)e * 43691u) >> 17);  // e/3, e < 98304
        float x = fminf(fmaxf(lbp[v], -LLR_MAX), LLR_MAX);
        float m;
        if (FIRST) {
            m = -x;                                   // msgs are all zero
        } else {
            int e0 = 3 * v;
            int j  = e - e0;                          // e mod 3
            float m0 = mi[e0], m1 = mi[e0 + 1], m2 = mi[e0 + 2];
            float s = ((m0 + m1) + m2) - x;           // exact reference order
            float own = (j == 0) ? m0 : ((j == 1) ? m1 : m2);
            m = s - own;                              // vn-extrinsic
        }
        unsigned neg = (m < 0.0f) ? 0x80000000u : 0u; // sign(0) -> +1
        float mg = phi_fast(fabsf(m), lt, et);
        g[t] = __uint_as_float(__float_as_uint(mg) | neg);
    }
    float a0 = fabsf(g[0]), a1 = fabsf(g[1]), a2 = fabsf(g[2]);
    float a3 = fabsf(g[3]), a4 = fabsf(g[4]), a5 = fabsf(g[5]);
    float ms = ((((a0 + a1) + a2) + a3) + a4) + a5;   // reference left-fold
    unsigned all6 = (__float_as_uint(g[0]) ^ __float_as_uint(g[1])
                   ^ __float_as_uint(g[2]) ^ __float_as_uint(g[3])
                   ^ __float_as_uint(g[4]) ^ __float_as_uint(g[5]))
                  & 0x80000000u;
#pragma unroll
    for (int t = 0; t < 6; ++t) {
        int e = c + (t << 13);
        float o = phi_fast(ms - fabsf(g[t]), lt, et);
        unsigned sg = all6 ^ (__float_as_uint(g[t]) & 0x80000000u);
        mo[e] = __uint_as_float(__float_as_uint(o) ^ sg);
    }
}

// ---- single cooperative kernel: 8 CN phases + final VN ----
__global__ __launch_bounds__(256)
void ldpc_coop(const float* __restrict__ llr, float* __restrict__ buf0,
               float* __restrict__ buf1, float* __restrict__ outv)
{
    __shared__ double2 lt[256];  // {1/t, log t} (4 KB)
    __shared__ double  et[256];  // 2^(j/256)    (2 KB)
    {
        int tid = threadIdx.x;
        double t = 1.0 + tid * 0.00390625;           // 1 + idx/256
        double r0 = (double)__builtin_amdgcn_rcpf((float)t);
        r0 = __builtin_fma(__builtin_fma(-t, r0, 1.0), r0, r0);
        r0 = __builtin_fma(__builtin_fma(-t, r0, 1.0), r0, r0);
        lt[tid] = make_double2(r0, lean_log(t));
        et[tid] = lean_exp(tid * EXP_STEP);
    }
    __syncthreads();

    cg::grid_group grid = cg::this_grid();
    const int tid = threadIdx.x;
    const int nvb = gridDim.x;

    // ---- iteration 0 (FIRST): msgs implicitly zero; writes buf0 ----
    for (int vb = blockIdx.x; vb < 4096; vb += nvb) {
        int seq = vb >> 3;
        int b   = (vb & 7) * 16 + (seq >> 5);        // 16 batches per XCD
        int c   = (seq & 31) * 256 + tid;
        cn_body<1>(llr, buf0, buf0, b, c, lt, et);
    }
    __threadfence();
    grid.sync();

    const float* cur = buf0;
    for (int it = 1; it < NUM_ITER; ++it) {
        float* dst = (it & 1) ? buf1 : buf0;
        for (int vb = blockIdx.x; vb < 4096; vb += nvb) {
            int seq = vb >> 3;
            int b   = (vb & 7) * 16 + (seq >> 5);
            int c   = (seq & 31) * 256 + tid;
            cn_body<0>(llr, cur, dst, b, c, lt, et);
        }
        __threadfence();
        grid.sync();
        cur = dst;                                    // it=7 -> buf1
    }

    // ---- final marginalize ----
    for (int vb = blockIdx.x; vb < 8192; vb += nvb) {
        int seq = vb >> 3;
        int b   = (vb & 7) * 16 + (seq >> 6);
        int v   = (seq & 63) * 256 + tid;
        float x = fminf(fmaxf(llr[(size_t)b * NUM_VNS + v], -LLR_MAX), LLR_MAX);
        const float* mb = cur + (size_t)b * NUM_EDGES;
        int e = 3 * v;
        float s = ((mb[e] + mb[e + 1]) + mb[e + 2]) - x;  // exact order
        outv[(size_t)b * NUM_VNS + v] = -s;
    }
}

// ---- r20 multi-launch fallback kernels ----
template<int FIRST>
__global__ __launch_bounds__(256)
void cn_fused(const float* __restrict__ llr, const float* __restrict__ msgIn,
              float* __restrict__ msgOut)
{
    __shared__ double2 lt[256];
    __shared__ double  et[256];
    {
        int tid = threadIdx.x;
        double t = 1.0 + tid * 0.00390625;
        double r0 = (double)__builtin_amdgcn_rcpf((float)t);
        r0 = __builtin_fma(__builtin_fma(-t, r0, 1.0), r0, r0);
        r0 = __builtin_fma(__builtin_fma(-t, r0, 1.0), r0, r0);
        lt[tid] = make_double2(r0, lean_log(t));
        et[tid] = lean_exp(tid * EXP_STEP);
    }
    __syncthreads();

    int bid = blockIdx.x;
    int seq = bid >> 3;
    int b   = (bid & 7) * 16 + (seq >> 5);
    int c   = (seq & 31) * 256 + threadIdx.x;
    cn_body<FIRST>(llr, FIRST ? msgOut : msgIn, msgOut, b, c, lt, et);
}

__global__ __launch_bounds__(256)
void vn_final(const float* __restrict__ llr, const float* __restrict__ msg,
              float* __restrict__ outv)
{
    int bid = blockIdx.x;
    int seq = bid >> 3;
    int b   = (bid & 7) * 16 + (seq >> 6);
    int v   = (seq & 63) * 256 + threadIdx.x;
    float x = fminf(fmaxf(llr[(size_t)b * NUM_VNS + v], -LLR_MAX), LLR_MAX);
    const float* mb = msg + (size_t)b * NUM_EDGES;
    int e = 3 * v;
    float s = ((mb[e] + mb[e + 1]) + mb[e + 2]) - x;
    outv[(size_t)b * NUM_VNS + v] = -s;
}

template<int FIRST, int LAST>
__global__ __launch_bounds__(256)
void vn_kernel(const float* __restrict__ llr, const float* __restrict__ msg,
               float* __restrict__ outv)
{
    int gid = blockIdx.x * 256 + threadIdx.x;
    int b = gid >> 14;
    int v = gid & 16383;
    float x = fminf(fmaxf(llr[gid], -LLR_MAX), LLR_MAX);
    float s;
    if (FIRST) {
        s = -x;
    } else {
        const float* mb = msg + (size_t)b * NUM_EDGES;
        int e = 3 * v;
        s = ((mb[e] + mb[e + 1]) + mb[e + 2]) - x;
    }
    outv[gid] = LAST ? -s : s;
}

template<int FIRST>
__global__ __launch_bounds__(256)
void cn_kernel(float* __restrict__ msg, const float* __restrict__ vtot)
{
    int gid = blockIdx.x * 256 + threadIdx.x;
    int b = gid >> 13;
    int c = gid & 8191;
    float* mb = msg + (size_t)b * NUM_EDGES;
    const float* vt = vtot + (size_t)b * NUM_VNS;

    float g[6];
#pragma unroll
    for (int t = 0; t < 6; ++t) {
        int e = c + (t << 13);
        int v = (int)(((unsigned)e * 43691u) >> 17);
        float m = FIRST ? vt[v] : (vt[v] - mb[e]);
        unsigned neg = (m < 0.0f) ? 0x80000000u : 0u;
        float mg = phi_f(fabsf(m));
        g[t] = __uint_as_float(__float_as_uint(mg) | neg);
    }
    float a0 = fabsf(g[0]), a1 = fabsf(g[1]), a2 = fabsf(g[2]);
    float a3 = fabsf(g[3]), a4 = fabsf(g[4]), a5 = fabsf(g[5]);
    float ms = ((((a0 + a1) + a2) + a3) + a4) + a5;
    unsigned all6 = (__float_as_uint(g[0]) ^ __float_as_uint(g[1])
                   ^ __float_as_uint(g[2]) ^ __float_as_uint(g[3])
                   ^ __float_as_uint(g[4]) ^ __float_as_uint(g[5]))
                  & 0x80000000u;
#pragma unroll
    for (int t = 0; t < 6; ++t) {
        int e = c + (t << 13);
        float o = phi_f(ms - fabsf(g[t]));
        unsigned sg = all6 ^ (__float_as_uint(g[t]) & 0x80000000u);
        mb[e] = __uint_as_float(__float_as_uint(o) ^ sg);
    }
}

extern "C" void kernel_launch(void* const* d_in, const int* in_sizes, int n_in,
                              void* d_out, int out_size, void* d_ws, size_t ws_size,
                              hipStream_t stream) {
    const float* llr = (const float*)d_in[0];
    float* out = (float*)d_out;

    const int VNB = BATCH * NUM_VNS / 256;             // 8192 blocks
    const int CNB = BATCH * NUM_CNS / 256;             // 4096 blocks
    const size_t MSGSZ = (size_t)BATCH * NUM_EDGES;    // 6.29M floats = 24 MB

    if (ws_size >= 2 * MSGSZ * sizeof(float)) {
        float* buf0 = (float*)d_ws;
        float* buf1 = buf0 + MSGSZ;

        // ---- preferred: single cooperative launch ----
        int maxB = 0, numCU = 0, dev = 0;
        hipError_t eo = hipOccupancyMaxActiveBlocksPerMultiprocessor(
            &maxB, ldpc_coop, 256, 0);
        hipError_t ed = hipGetDevice(&dev);
        hipError_t ea = hipDeviceGetAttribute(
            &numCU, hipDeviceAttributeMultiprocessorCount, dev);
        if (eo == hipSuccess && ed == hipSuccess && ea == hipSuccess &&
            maxB > 0 && numCU > 0) {
            int grid = maxB * numCU;
            if (grid > 4096) grid = 4096;
            void* args[] = { (void*)&llr, (void*)&buf0, (void*)&buf1,
                             (void*)&out };
            hipError_t el = hipLaunchCooperativeKernel(
                (const void*)ldpc_coop, dim3(grid), dim3(256), args, 0, stream);
            if (el == hipSuccess) return;
        }

        // ---- r20 multi-launch path ----
        cn_fused<1><<<CNB, 256, 0, stream>>>(llr, buf0, buf0);
        for (int it = 1; it < NUM_ITER; ++it) {
            float* in  = (it & 1) ? buf0 : buf1;
            float* dst = (it & 1) ? buf1 : buf0;
            cn_fused<0><<<CNB, 256, 0, stream>>>(llr, in, dst);
        }
        vn_final<<<VNB, 256, 0, stream>>>(llr, buf1, out);
    } else {
        // ---- r12 fallback: 32 MB workspace ----
        float* msg  = (float*)d_ws;
        float* vtot = msg + MSGSZ;
        vn_kernel<1, 0><<<VNB, 256, 0, stream>>>(llr, msg, vtot);
        cn_kernel<1><<<CNB, 256, 0, stream>>>(msg, vtot);
        for (int it = 1; it < NUM_ITER; ++it) {
            vn_kernel<0, 0><<<VNB, 256, 0, stream>>>(llr, msg, vtot);
            cn_kernel<0><<<CNB, 256, 0, stream>>>(msg, vtot);
        }
        vn_kernel<0, 1><<<VNB, 256, 0, stream>>>(llr, msg, out);
    }
}

// Round 23
// 410.137 us; speedup vs baseline: 3.6630x; 3.6630x over previous
//
#include <hip/hip_runtime.h>

// LDPC BP decoder, (3,6)-regular — fused full-chip version, table-phi v5.
// Edge e (vn order) = 3v+j; c = e mod 8192, t = e div 8192, e = c + 8192t.
//
// r22 post-mortem: cooperative grid.sync costs ~145us each on MI355X (8
// XCD L2-atomic spin) -> single-kernel fusion abandoned; multi-launch is
// optimal. r23 = r20 structure + (a) final marginalize fused into CN
// iteration 8 via atomicAdd (final sum has NO amplification; reorder costs
// <=1e-5), last kernel writes no msg buffer; out zeroed by hipMemsetAsync
// (graph-capturable). (b) 2 CNs/thread -> 2048 blocks = exactly one
// occupancy cohort (4096 blocks was two). Phi chain byte-identical to r20.

constexpr int NUM_VNS   = 16384;
constexpr int NUM_CNS   = 8192;
constexpr int NUM_EDGES = 49152;
constexpr int BATCH     = 128;
constexpr int NUM_ITER  = 8;
constexpr float LLR_MAX = 20.0f;
constexpr float PHI_MIN = 8.5e-8f;
constexpr float PHI_MAX = 16.635532f;

// ---- full-accuracy reference primitives (table init + fallback path) ----
__device__ __forceinline__ double lean_exp(double x) {
    double t = x * 1.4426950408889634;
    double k = __builtin_rint(t);
    double r = __builtin_fma(-k, 0.6931471805599453, x);
    r = __builtin_fma(-k, 2.3190468138462996e-17, r);
    double p = 1.0 / 3628800.0;                  // Taylor deg 10, |r|<=0.347
    p = __builtin_fma(p, r, 1.0 / 362880.0);
    p = __builtin_fma(p, r, 1.0 / 40320.0);
    p = __builtin_fma(p, r, 1.0 / 5040.0);
    p = __builtin_fma(p, r, 1.0 / 720.0);
    p = __builtin_fma(p, r, 1.0 / 120.0);
    p = __builtin_fma(p, r, 1.0 / 24.0);
    p = __builtin_fma(p, r, 1.0 / 6.0);
    p = __builtin_fma(p, r, 0.5);
    p = __builtin_fma(p, r, 1.0);
    p = __builtin_fma(p, r, 1.0);
    int ik = (int)k;                              // k in [0,24]
    double s = __hiloint2double((1023 + ik) << 20, 0);
    return p * s;
}

__device__ __forceinline__ double lean_log(double v) {
    int hv = __double2hiint(v);
    int lv = __double2loint(v);
    int e  = (hv >> 20) - 1023;
    double m = __hiloint2double((hv & 0x000FFFFF) | 0x3FF00000, lv);
    if (m >= 1.4142135623730951) { m *= 0.5; e += 1; }   // m in [0.7071,1.4142)
    double t = m - 1.0;
    double d = t + 2.0;
    double r = (double)__builtin_amdgcn_rcpf((float)d);
    r = __builtin_fma(__builtin_fma(-d, r, 1.0), r, r);
    double u = t * r;
    double w = u * u;
    double P = 2.0 / 13.0;                        // 2*artanh: deg 6 in w
    P = __builtin_fma(P, w, 2.0 / 11.0);
    P = __builtin_fma(P, w, 2.0 / 9.0);
    P = __builtin_fma(P, w, 2.0 / 7.0);
    P = __builtin_fma(P, w, 2.0 / 5.0);
    P = __builtin_fma(P, w, 2.0 / 3.0);
    P = __builtin_fma(P, w, 2.0);
    double lm = u * P;
    return __builtin_fma((double)e, 0.6931471805599453, lm);
}

__device__ __forceinline__ float phi_f(float xf) {
    xf = fminf(fmaxf(xf, PHI_MIN), PHI_MAX);
    float exf = (float)lean_exp((double)xf);
    float af = exf + 1.0f;
    float bf = exf - 1.0f;
    float la = (float)lean_log((double)af);
    float lb = (float)lean_log((double)bf);
    return la - lb;
}

// ---- fast table primitives (main path) ----
constexpr double EXP_STEP = 0.0027076061740622864;  // double(ln2/256)
constexpr double EXP_INV  = 369.32993046757465;     // 256/ln2

// e^x, x in [0, 16.64]; rel err <= r^3/6 ~ 2^-31.2, and -> 0 as x -> 0.
__device__ __forceinline__ double fast_exp(double x, const double* et) {
    double kd = __builtin_rint(x * EXP_INV);
    double r  = __builtin_fma(-kd, EXP_STEP, x);     // |r| <= 0.001354
    int n = (int)kd;                                 // [0, 6145]
    double p = __builtin_fma(r, __builtin_fma(r, 0.5, 1.0), 1.0);  // deg 2
    double s = et[n & 255];                          // 2^(j/256)
    int sh = __double2hiint(s) + ((n >> 8) << 20);   // * 2^k
    s = __hiloint2double(sh, __double2loint(s));
    return p * s;
}

// log(v), v an exact f32 in [2^-23, 2^25]; abs err ~2^-34.
__device__ __forceinline__ double fast_log(double v, const double2* lt) {
    int hv = __double2hiint(v);
    int lv = __double2loint(v);
    int E  = (hv >> 20) - 1023;
    double m = __hiloint2double((hv & 0x000FFFFF) | 0x3FF00000, lv); // [1,2)
    int idx = (hv >> 12) & 255;
    double2 te = lt[idx];                            // {1/t, log t}
    double t = __hiloint2double(0x3FF00000 | (idx << 12), 0);        // 1+idx/256
    double d = m - t;                                // exact (Sterbenz)
    double f = d * te.x;                             // d / t, f in [0, 2^-8)
    double P = __builtin_fma(f, 1.0 / 3.0, -0.5);
    double q = __builtin_fma(f * f, P, f);           // log1p(f), deg 3
    return __builtin_fma((double)E, 0.6931471805599453, te.y + q);
}

__device__ __forceinline__ float phi_fast(float xf, const double2* lt,
                                          const double* et) {
    xf = fminf(fmaxf(xf, PHI_MIN), PHI_MAX);
    float exf = (float)fast_exp((double)xf, et);
    float af = exf + 1.0f;
    float bf = exf - 1.0f;
    float la = (float)fast_log((double)af, lt);
    float lb = (float)fast_log((double)bf, lt);
    return la - lb;
}

// ---- fused CN kernel, 2 CNs/thread (c, c+4096), XCD-sharded. ----
// FIRST: msgs implicitly zero. LAST: no msg writes; atomically accumulates
// the final marginalize out[v] = x - m0 - m1 - m2 (final sum, no
// amplification -> reorder safe).
template<int FIRST, int LAST>
__global__ __launch_bounds__(256)
void cn_fused2(const float* __restrict__ llr, const float* __restrict__ msgIn,
               float* __restrict__ msgOut, float* __restrict__ outv)
{
    __shared__ double2 lt[256];  // {1/t, log t} (4 KB)
    __shared__ double  et[256];  // 2^(j/256)    (2 KB)
    {
        int tid = threadIdx.x;
        double t = 1.0 + tid * 0.00390625;           // 1 + idx/256
        double r0 = (double)__builtin_amdgcn_rcpf((float)t);
        r0 = __builtin_fma(__builtin_fma(-t, r0, 1.0), r0, r0);
        r0 = __builtin_fma(__builtin_fma(-t, r0, 1.0), r0, r0);
        lt[tid] = make_double2(r0, lean_log(t));
        et[tid] = lean_exp(tid * EXP_STEP);
    }
    __syncthreads();

    // 2048 blocks: bid&7 = XCD; each XCD owns 16 whole batches.
    int bid = blockIdx.x;
    int seq = bid >> 3;                          // [0, 256)
    int b   = (bid & 7) * 16 + (seq >> 4);       // 16 batches per XCD
    int ch  = (seq & 15) * 256 + threadIdx.x;    // [0, 4096)

    const float* mi = msgIn + (size_t)b * NUM_EDGES;
    float* mo = msgOut + (size_t)b * NUM_EDGES;
    const float* lbp = llr + (size_t)b * NUM_VNS;
    float* ob = outv + (size_t)b * NUM_VNS;

#pragma unroll
    for (int h = 0; h < 2; ++h) {
        int c = ch + (h ? 4096 : 0);

        float g[6];                                 // signed mags (sign in bit)
#pragma unroll
        for (int t = 0; t < 6; ++t) {
            int e = c + (t << 13);
            int v = (int)(((unsigned)e * 43691u) >> 17);  // e/3, e < 98304
            float x = fminf(fmaxf(lbp[v], -LLR_MAX), LLR_MAX);
            float m;
            if (FIRST) {
                m = -x;                                   // msgs are all zero
            } else {
                int e0 = 3 * v;
                int j  = e - e0;                          // e mod 3
                float m0 = mi[e0], m1 = mi[e0 + 1], m2 = mi[e0 + 2];
                float s = ((m0 + m1) + m2) - x;           // exact ref order
                float own = (j == 0) ? m0 : ((j == 1) ? m1 : m2);
                m = s - own;                              // vn-extrinsic
            }
            unsigned neg = (m < 0.0f) ? 0x80000000u : 0u; // sign(0) -> +1
            float mg = phi_fast(fabsf(m), lt, et);
            g[t] = __uint_as_float(__float_as_uint(mg) | neg);
        }
        float a0 = fabsf(g[0]), a1 = fabsf(g[1]), a2 = fabsf(g[2]);
        float a3 = fabsf(g[3]), a4 = fabsf(g[4]), a5 = fabsf(g[5]);
        float ms = ((((a0 + a1) + a2) + a3) + a4) + a5;   // ref left-fold
        unsigned all6 = (__float_as_uint(g[0]) ^ __float_as_uint(g[1])
                       ^ __float_as_uint(g[2]) ^ __float_as_uint(g[3])
                       ^ __float_as_uint(g[4]) ^ __float_as_uint(g[5]))
                      & 0x80000000u;
#pragma unroll
        for (int t = 0; t < 6; ++t) {
            int e = c + (t << 13);
            float o = phi_fast(ms - fabsf(g[t]), lt, et);
            unsigned sg = all6 ^ (__float_as_uint(g[t]) & 0x80000000u);
            float osg = __uint_as_float(__float_as_uint(o) ^ sg);
            if (LAST) {
                int v = (int)(((unsigned)e * 43691u) >> 17);
                int j = e - 3 * v;
                float contrib = -osg;
                if (j == 0) {
                    float x = fminf(fmaxf(lbp[v], -LLR_MAX), LLR_MAX);
                    contrib = x - osg;
                }
                atomicAdd(&ob[v], contrib);
            } else {
                mo[e] = osg;
            }
        }
    }
}

// ---- r12 fallback kernels (lean phi, 32 MB workspace) ----
template<int FIRST, int LAST>
__global__ __launch_bounds__(256)
void vn_kernel(const float* __restrict__ llr, const float* __restrict__ msg,
               float* __restrict__ outv)
{
    int gid = blockIdx.x * 256 + threadIdx.x;       // b*16384 + v
    int b = gid >> 14;
    int v = gid & 16383;
    float x = fminf(fmaxf(llr[gid], -LLR_MAX), LLR_MAX);
    float s;
    if (FIRST) {
        s = -x;
    } else {
        const float* mb = msg + (size_t)b * NUM_EDGES;
        int e = 3 * v;
        s = ((mb[e] + mb[e + 1]) + mb[e + 2]) - x;
    }
    outv[gid] = LAST ? -s : s;
}

template<int FIRST>
__global__ __launch_bounds__(256)
void cn_kernel(float* __restrict__ msg, const float* __restrict__ vtot)
{
    int gid = blockIdx.x * 256 + threadIdx.x;       // b*8192 + c
    int b = gid >> 13;
    int c = gid & 8191;
    float* mb = msg + (size_t)b * NUM_EDGES;
    const float* vt = vtot + (size_t)b * NUM_VNS;

    float g[6];
#pragma unroll
    for (int t = 0; t < 6; ++t) {
        int e = c + (t << 13);
        int v = (int)(((unsigned)e * 43691u) >> 17);
        float m = FIRST ? vt[v] : (vt[v] - mb[e]);
        unsigned neg = (m < 0.0f) ? 0x80000000u : 0u;
        float mg = phi_f(fabsf(m));
        g[t] = __uint_as_float(__float_as_uint(mg) | neg);
    }
    float a0 = fabsf(g[0]), a1 = fabsf(g[1]), a2 = fabsf(g[2]);
    float a3 = fabsf(g[3]), a4 = fabsf(g[4]), a5 = fabsf(g[5]);
    float ms = ((((a0 + a1) + a2) + a3) + a4) + a5;
    unsigned all6 = (__float_as_uint(g[0]) ^ __float_as_uint(g[1])
                   ^ __float_as_uint(g[2]) ^ __float_as_uint(g[3])
                   ^ __float_as_uint(g[4]) ^ __float_as_uint(g[5]))
                  & 0x80000000u;
#pragma unroll
    for (int t = 0; t < 6; ++t) {
        int e = c + (t << 13);
        float o = phi_f(ms - fabsf(g[t]));
        unsigned sg = all6 ^ (__float_as_uint(g[t]) & 0x80000000u);
        mb[e] = __uint_as_float(__float_as_uint(o) ^ sg);
    }
}

extern "C" void kernel_launch(void* const* d_in, const int* in_sizes, int n_in,
                              void* d_out, int out_size, void* d_ws, size_t ws_size,
                              hipStream_t stream) {
    const float* llr = (const float*)d_in[0];
    float* out = (float*)d_out;

    const int VNB  = BATCH * NUM_VNS / 256;            // 8192 blocks
    const int CNB  = BATCH * NUM_CNS / 256;            // 4096 blocks
    const int CNB2 = BATCH * (NUM_CNS / 2) / 256;      // 2048 blocks
    const size_t MSGSZ = (size_t)BATCH * NUM_EDGES;    // 6.29M floats = 24 MB

    if (ws_size >= 2 * MSGSZ * sizeof(float)) {
        float* buf0 = (float*)d_ws;
        float* buf1 = buf0 + MSGSZ;

        // zero out for the fused-finale atomics (graph-capturable)
        hipMemsetAsync(out, 0, (size_t)out_size * sizeof(float), stream);

        // it0 (FIRST) writes buf0; it1..6 ping-pong; it7 (LAST) reads buf0
        cn_fused2<1, 0><<<CNB2, 256, 0, stream>>>(llr, buf0, buf0, out);
        for (int it = 1; it < NUM_ITER - 1; ++it) {
            float* in  = (it & 1) ? buf0 : buf1;
            float* dst = (it & 1) ? buf1 : buf0;
            cn_fused2<0, 0><<<CNB2, 256, 0, stream>>>(llr, in, dst, out);
        }
        // it6 wrote buf0 (it=6 even -> dst=buf0); it7 reads buf0, atomics out
        cn_fused2<0, 1><<<CNB2, 256, 0, stream>>>(llr, buf0, buf1, out);
    } else {
        // ---- r12 fallback: 32 MB workspace ----
        float* msg  = (float*)d_ws;
        float* vtot = msg + MSGSZ;
        vn_kernel<1, 0><<<VNB, 256, 0, stream>>>(llr, msg, vtot);
        cn_kernel<1><<<CNB, 256, 0, stream>>>(msg, vtot);
        for (int it = 1; it < NUM_ITER; ++it) {
            vn_kernel<0, 0><<<VNB, 256, 0, stream>>>(llr, msg, vtot);
            cn_kernel<0><<<CNB, 256, 0, stream>>>(msg, vtot);
        }
        vn_kernel<0, 1><<<VNB, 256, 0, stream>>>(llr, msg, out);
    }
}

// Round 24
// 203.756 us; speedup vs baseline: 7.3731x; 2.0129x over previous
//
#include <hip/hip_runtime.h>

// LDPC BP decoder, (3,6)-regular — fused full-chip version, table-phi v4.
// Edge e (vn order) = 3v+j; c = e mod 8192, t = e div 8192, e = c + 8192t.
//
// FINAL FORM = r20 verbatim (203.8us, absmax 0.25). Ledger:
//  - phi must be ~CR f32 at every intermediate (hw exp r10: 10.5 FAIL;
//    hw log r19: 10.0 FAIL; ~2^-31 table-f64 primitives: 0.25 PASS).
//  - op-count cuts in that framework: 610 -> 204us (r16 tables -56,
//    r18/r20 poly-deg shaves -14).
//  - neutral: ILP (r14), XCD shard (r15), gather split + b128 tables (r17),
//    2 CN/thread (r23).
//  - regressions: cooperative grid.sync ~145us each (r22, 8-XCD L2-atomic
//    spin); atomicAdd finale ~240us (r23, ~52G atomics/s L2 wall).

constexpr int NUM_VNS   = 16384;
constexpr int NUM_CNS   = 8192;
constexpr int NUM_EDGES = 49152;
constexpr int BATCH     = 128;
constexpr int NUM_ITER  = 8;
constexpr float LLR_MAX = 20.0f;
constexpr float PHI_MIN = 8.5e-8f;
constexpr float PHI_MAX = 16.635532f;

// ---- full-accuracy reference primitives (table init + fallback path) ----
__device__ __forceinline__ double lean_exp(double x) {
    double t = x * 1.4426950408889634;
    double k = __builtin_rint(t);
    double r = __builtin_fma(-k, 0.6931471805599453, x);
    r = __builtin_fma(-k, 2.3190468138462996e-17, r);
    double p = 1.0 / 3628800.0;                  // Taylor deg 10, |r|<=0.347
    p = __builtin_fma(p, r, 1.0 / 362880.0);
    p = __builtin_fma(p, r, 1.0 / 40320.0);
    p = __builtin_fma(p, r, 1.0 / 5040.0);
    p = __builtin_fma(p, r, 1.0 / 720.0);
    p = __builtin_fma(p, r, 1.0 / 120.0);
    p = __builtin_fma(p, r, 1.0 / 24.0);
    p = __builtin_fma(p, r, 1.0 / 6.0);
    p = __builtin_fma(p, r, 0.5);
    p = __builtin_fma(p, r, 1.0);
    p = __builtin_fma(p, r, 1.0);
    int ik = (int)k;                              // k in [0,24]
    double s = __hiloint2double((1023 + ik) << 20, 0);
    return p * s;
}

__device__ __forceinline__ double lean_log(double v) {
    int hv = __double2hiint(v);
    int lv = __double2loint(v);
    int e  = (hv >> 20) - 1023;
    double m = __hiloint2double((hv & 0x000FFFFF) | 0x3FF00000, lv);
    if (m >= 1.4142135623730951) { m *= 0.5; e += 1; }   // m in [0.7071,1.4142)
    double t = m - 1.0;
    double d = t + 2.0;
    double r = (double)__builtin_amdgcn_rcpf((float)d);
    r = __builtin_fma(__builtin_fma(-d, r, 1.0), r, r);
    double u = t * r;
    double w = u * u;
    double P = 2.0 / 13.0;                        // 2*artanh: deg 6 in w
    P = __builtin_fma(P, w, 2.0 / 11.0);
    P = __builtin_fma(P, w, 2.0 / 9.0);
    P = __builtin_fma(P, w, 2.0 / 7.0);
    P = __builtin_fma(P, w, 2.0 / 5.0);
    P = __builtin_fma(P, w, 2.0 / 3.0);
    P = __builtin_fma(P, w, 2.0);
    double lm = u * P;
    return __builtin_fma((double)e, 0.6931471805599453, lm);
}

__device__ __forceinline__ float phi_f(float xf) {
    xf = fminf(fmaxf(xf, PHI_MIN), PHI_MAX);
    float exf = (float)lean_exp((double)xf);
    float af = exf + 1.0f;
    float bf = exf - 1.0f;
    float la = (float)lean_log((double)af);
    float lb = (float)lean_log((double)bf);
    return la - lb;
}

// ---- fast table primitives (main path) ----
constexpr double EXP_STEP = 0.0027076061740622864;  // double(ln2/256)
constexpr double EXP_INV  = 369.32993046757465;     // 256/ln2

// e^x, x in [0, 16.64]; rel err <= r^3/6 ~ 2^-31.2, and -> 0 as x -> 0.
__device__ __forceinline__ double fast_exp(double x, const double* et) {
    double kd = __builtin_rint(x * EXP_INV);
    double r  = __builtin_fma(-kd, EXP_STEP, x);     // |r| <= 0.001354
    int n = (int)kd;                                 // [0, 6145]
    double p = __builtin_fma(r, __builtin_fma(r, 0.5, 1.0), 1.0);  // deg 2
    double s = et[n & 255];                          // 2^(j/256)
    int sh = __double2hiint(s) + ((n >> 8) << 20);   // * 2^k
    s = __hiloint2double(sh, __double2loint(s));
    return p * s;
}

// log(v), v an exact f32 in [2^-23, 2^25]; abs err ~2^-34.
__device__ __forceinline__ double fast_log(double v, const double2* lt) {
    int hv = __double2hiint(v);
    int lv = __double2loint(v);
    int E  = (hv >> 20) - 1023;
    double m = __hiloint2double((hv & 0x000FFFFF) | 0x3FF00000, lv); // [1,2)
    int idx = (hv >> 12) & 255;
    double2 te = lt[idx];                            // {1/t, log t}
    double t = __hiloint2double(0x3FF00000 | (idx << 12), 0);        // 1+idx/256
    double d = m - t;                                // exact (Sterbenz)
    double f = d * te.x;                             // d / t, f in [0, 2^-8)
    double P = __builtin_fma(f, 1.0 / 3.0, -0.5);
    double q = __builtin_fma(f * f, P, f);           // log1p(f), deg 3
    return __builtin_fma((double)E, 0.6931471805599453, te.y + q);
}

// literal reference chain with table primitives (same f32 rounding points).
__device__ __forceinline__ float phi_fast(float xf, const double2* lt,
                                          const double* et) {
    xf = fminf(fmaxf(xf, PHI_MIN), PHI_MAX);
    float exf = (float)fast_exp((double)xf, et);
    float af = exf + 1.0f;
    float bf = exf - 1.0f;
    float la = (float)fast_log((double)af, lt);
    float lb = (float)fast_log((double)bf, lt);
    return la - lb;
}

// ---- fused CN kernel, XCD-sharded: one thread per (b, c). ----
template<int FIRST>
__global__ __launch_bounds__(256)
void cn_fused(const float* __restrict__ llr, const float* __restrict__ msgIn,
              float* __restrict__ msgOut)
{
    __shared__ double2 lt[256];  // {1/t, log t} per 256 mantissa bins (4 KB)
    __shared__ double  et[256];  // 2^(j/256)                        (2 KB)
    {
        int tid = threadIdx.x;
        {
            double t = 1.0 + tid * 0.00390625;       // 1 + idx/256
            double r0 = (double)__builtin_amdgcn_rcpf((float)t);
            r0 = __builtin_fma(__builtin_fma(-t, r0, 1.0), r0, r0);
            r0 = __builtin_fma(__builtin_fma(-t, r0, 1.0), r0, r0);
            lt[tid] = make_double2(r0, lean_log(t));
        }
        et[tid] = lean_exp(tid * EXP_STEP);
    }
    __syncthreads();

    int bid = blockIdx.x;
    int seq = bid >> 3;                          // [0, 512)
    int b   = (bid & 7) * 16 + (seq >> 5);       // 16 batches per XCD
    int c   = (seq & 31) * 256 + threadIdx.x;    // [0, 8192)

    const float* mi = msgIn + (size_t)b * NUM_EDGES;
    float* mo = msgOut + (size_t)b * NUM_EDGES;
    const float* lbp = llr + (size_t)b * NUM_VNS;

    float g[6];                                     // signed mags (sign in bit)
#pragma unroll
    for (int t = 0; t < 6; ++t) {
        int e = c + (t << 13);
        int v = (int)(((unsigned)e * 43691u) >> 17);  // e/3, e < 98304
        float x = fminf(fmaxf(lbp[v], -LLR_MAX), LLR_MAX);
        float m;
        if (FIRST) {
            m = -x;                                   // msgs are all zero
        } else {
            int e0 = 3 * v;
            int j  = e - e0;                          // e mod 3
            float m0 = mi[e0], m1 = mi[e0 + 1], m2 = mi[e0 + 2];
            float s = ((m0 + m1) + m2) - x;           // exact reference order
            float own = (j == 0) ? m0 : ((j == 1) ? m1 : m2);
            m = s - own;                              // vn-extrinsic
        }
        unsigned neg = (m < 0.0f) ? 0x80000000u : 0u; // sign(0) -> +1
        float mg = phi_fast(fabsf(m), lt, et);
        g[t] = __uint_as_float(__float_as_uint(mg) | neg);
    }
    float a0 = fabsf(g[0]), a1 = fabsf(g[1]), a2 = fabsf(g[2]);
    float a3 = fabsf(g[3]), a4 = fabsf(g[4]), a5 = fabsf(g[5]);
    float ms = ((((a0 + a1) + a2) + a3) + a4) + a5;   // reference left-fold
    unsigned all6 = (__float_as_uint(g[0]) ^ __float_as_uint(g[1])
                   ^ __float_as_uint(g[2]) ^ __float_as_uint(g[3])
                   ^ __float_as_uint(g[4]) ^ __float_as_uint(g[5]))
                  & 0x80000000u;
#pragma unroll
    for (int t = 0; t < 6; ++t) {
        int e = c + (t << 13);
        float o = phi_fast(ms - fabsf(g[t]), lt, et);
        unsigned sg = all6 ^ (__float_as_uint(g[t]) & 0x80000000u);
        mo[e] = __uint_as_float(__float_as_uint(o) ^ sg);
    }
}

// ---- final marginalize, XCD-sharded to match cn_fused's batch->XCD map. ----
__global__ __launch_bounds__(256)
void vn_final(const float* __restrict__ llr, const float* __restrict__ msg,
              float* __restrict__ outv)
{
    int bid = blockIdx.x;                        // 8192 blocks
    int seq = bid >> 3;                          // [0, 1024)
    int b   = (bid & 7) * 16 + (seq >> 6);       // 16 batches per XCD
    int v   = (seq & 63) * 256 + threadIdx.x;    // [0, 16384)
    float x = fminf(fmaxf(llr[(size_t)b * NUM_VNS + v], -LLR_MAX), LLR_MAX);
    const float* mb = msg + (size_t)b * NUM_EDGES;
    int e = 3 * v;
    float s = ((mb[e] + mb[e + 1]) + mb[e + 2]) - x;  // exact reference order
    outv[(size_t)b * NUM_VNS + v] = -s;
}

// ---- VN kernel (r12 fallback). ----
template<int FIRST, int LAST>
__global__ __launch_bounds__(256)
void vn_kernel(const float* __restrict__ llr, const float* __restrict__ msg,
               float* __restrict__ outv)
{
    int gid = blockIdx.x * 256 + threadIdx.x;       // b*16384 + v
    int b = gid >> 14;
    int v = gid & 16383;
    float x = fminf(fmaxf(llr[gid], -LLR_MAX), LLR_MAX);
    float s;
    if (FIRST) {
        s = -x;
    } else {
        const float* mb = msg + (size_t)b * NUM_EDGES;
        int e = 3 * v;
        s = ((mb[e] + mb[e + 1]) + mb[e + 2]) - x;
    }
    outv[gid] = LAST ? -s : s;
}

// ---- CN kernel (r12 fallback, reads precomputed vtot). ----
template<int FIRST>
__global__ __launch_bounds__(256)
void cn_kernel(float* __restrict__ msg, const float* __restrict__ vtot)
{
    int gid = blockIdx.x * 256 + threadIdx.x;       // b*8192 + c
    int b = gid >> 13;
    int c = gid & 8191;
    float* mb = msg + (size_t)b * NUM_EDGES;
    const float* vt = vtot + (size_t)b * NUM_VNS;

    float g[6];
#pragma unroll
    for (int t = 0; t < 6; ++t) {
        int e = c + (t << 13);
        int v = (int)(((unsigned)e * 43691u) >> 17);
        float m = FIRST ? vt[v] : (vt[v] - mb[e]);
        unsigned neg = (m < 0.0f) ? 0x80000000u : 0u;
        float mg = phi_f(fabsf(m));
        g[t] = __uint_as_float(__float_as_uint(mg) | neg);
    }
    float a0 = fabsf(g[0]), a1 = fabsf(g[1]), a2 = fabsf(g[2]);
    float a3 = fabsf(g[3]), a4 = fabsf(g[4]), a5 = fabsf(g[5]);
    float ms = ((((a0 + a1) + a2) + a3) + a4) + a5;
    unsigned all6 = (__float_as_uint(g[0]) ^ __float_as_uint(g[1])
                   ^ __float_as_uint(g[2]) ^ __float_as_uint(g[3])
                   ^ __float_as_uint(g[4]) ^ __float_as_uint(g[5]))
                  & 0x80000000u;
#pragma unroll
    for (int t = 0; t < 6; ++t) {
        int e = c + (t << 13);
        float o = phi_f(ms - fabsf(g[t]));
        unsigned sg = all6 ^ (__float_as_uint(g[t]) & 0x80000000u);
        mb[e] = __uint_as_float(__float_as_uint(o) ^ sg);
    }
}

extern "C" void kernel_launch(void* const* d_in, const int* in_sizes, int n_in,
                              void* d_out, int out_size, void* d_ws, size_t ws_size,
                              hipStream_t stream) {
    const float* llr = (const float*)d_in[0];
    float* out = (float*)d_out;

    const int VNB = BATCH * NUM_VNS / 256;             // 8192 blocks
    const int CNB = BATCH * NUM_CNS / 256;             // 4096 blocks
    const size_t MSGSZ = (size_t)BATCH * NUM_EDGES;    // 6.29M floats = 24 MB

    if (ws_size >= 2 * MSGSZ * sizeof(float)) {
        // ---- fused path: 8 CN launches (double-buffered) + final VN ----
        float* buf0 = (float*)d_ws;
        float* buf1 = buf0 + MSGSZ;
        cn_fused<1><<<CNB, 256, 0, stream>>>(llr, buf0, buf0);     // writes buf0
        for (int it = 1; it < NUM_ITER; ++it) {
            float* in  = (it & 1) ? buf0 : buf1;
            float* dst = (it & 1) ? buf1 : buf0;
            cn_fused<0><<<CNB, 256, 0, stream>>>(llr, in, dst);
        }
        // NUM_ITER=8: last write was buf1 (it=7 -> dst=buf1)
        vn_final<<<VNB, 256, 0, stream>>>(llr, buf1, out);
    } else {
        // ---- r12 fallback: 32 MB workspace ----
        float* msg  = (float*)d_ws;
        float* vtot = msg + MSGSZ;
        vn_kernel<1, 0><<<VNB, 256, 0, stream>>>(llr, msg, vtot);
        cn_kernel<1><<<CNB, 256, 0, stream>>>(msg, vtot);
        for (int it = 1; it < NUM_ITER; ++it) {
            vn_kernel<0, 0><<<VNB, 256, 0, stream>>>(llr, msg, vtot);
            cn_kernel<0><<<CNB, 256, 0, stream>>>(msg, vtot);
        }
        vn_kernel<0, 1><<<VNB, 256, 0, stream>>>(llr, msg, out);
    }
}